// Round 3
// baseline (1288.150 us; speedup 1.0000x reference)
//
#include <hip/hip_runtime.h>
#include <cstdint>
#include <cstddef>

#define D_    768
#define ROWS  32768      // row pairs (B*N)
#define MTOT  65536      // interleaved rows: 2i = x1_i, 2i+1 = x2_i
#define HID   192
#define KMLP  1536
#define NMLP  384

typedef __attribute__((ext_vector_type(4))) float f32x4;
typedef __attribute__((ext_vector_type(8))) short s16x8;

__device__ inline unsigned short f2bf(float f) {
  union { float f; uint32_t u; } c; c.f = f;
  uint32_t r = c.u + 0x7FFFu + ((c.u >> 16) & 1u);
  return (unsigned short)(r >> 16);
}
__device__ inline float bf2f(unsigned short h) {
  union { uint32_t u; float f; } c; c.u = ((uint32_t)h) << 16;
  return c.f;
}

__device__ inline void gld_lds16(const void* g, void* l) {
  __builtin_amdgcn_global_load_lds(
      (const __attribute__((address_space(1))) void*)g,
      (__attribute__((address_space(3))) void*)l, 16, 0, 0);
}

// ---- x1,x2 fp32 -> xb bf16, pair-interleaved [65536, 768]
__global__ void k_convert_x(const float* __restrict__ x1, const float* __restrict__ x2,
                            unsigned short* __restrict__ xb) {
  const int r = blockIdx.x;               // output row
  const int c = threadIdx.x * 4;
  const float* src = ((r & 1) ? x2 : x1) + (size_t)(r >> 1) * D_ + c;
  float4 v = *(const float4*)src;
  union { unsigned short u[4]; uint2 p; } o;
  o.u[0] = f2bf(v.x); o.u[1] = f2bf(v.y); o.u[2] = f2bf(v.z); o.u[3] = f2bf(v.w);
  *(uint2*)(xb + (size_t)r * D_ + c) = o.p;
}

// ---- weight conversions
__global__ void k_convert_w(const float* __restrict__ Wq, const float* __restrict__ Wk,
                            const float* __restrict__ Wv, const float* __restrict__ W1,
                            unsigned short* __restrict__ Wqb, unsigned short* __restrict__ Wkb,
                            unsigned short* __restrict__ BtMain, unsigned short* __restrict__ BtMlp) {
  int idx = blockIdx.x * 256 + threadIdx.x;
  const int S = D_ * D_;
  if (idx < S) { Wqb[idx] = f2bf(Wq[idx]); return; }
  idx -= S;
  if (idx < S) { Wkb[idx] = f2bf(Wk[idx]); return; }
  idx -= S;
  if (idx < S) {
    int n = idx / D_, k = idx - n * D_;
    BtMain[idx] = f2bf(Wv[(size_t)k * D_ + n]);
    return;
  }
  idx -= S;
  if (idx < NMLP * KMLP) {
    int n = idx / KMLP, k = idx - n * KMLP;
    int cc = (n < HID) ? n : n - HID;
    int kk = (n < HID) ? k : ((k < D_) ? k + D_ : k - D_);
    BtMlp[idx] = f2bf(W1[(size_t)kk * HID + cc]);
  }
}

// ---- nk[j] = noise @ Wk ;  gn[a] = Wq[a][:] . nk  (fp32 throughout)
__global__ void k_nk(const float* __restrict__ noise, const float* __restrict__ Wk,
                     float* __restrict__ nk) {
  int j = blockIdx.x * 256 + threadIdx.x;
  if (j >= D_) return;
  float s = 0.f;
  for (int k = 0; k < D_; ++k) s += noise[k] * Wk[(size_t)k * D_ + j];
  nk[j] = s;
}
__global__ void k_gn(const float* __restrict__ Wq, const float* __restrict__ nk,
                     float* __restrict__ gn) {
  int a = blockIdx.x * 256 + threadIdx.x;
  if (a >= D_) return;
  float s = 0.f;
  for (int j = 0; j < D_; ++j) s += Wq[(size_t)a * D_ + j] * nk[j];
  gn[a] = s;
}

// ---- generic 128x128 bf16 GEMM (kept for the small G = Wq@Wk^T gemm)
template<int NTILES, bool SWIZ, int KK>
__launch_bounds__(256)
__global__ void k_gemm(const unsigned short* __restrict__ A,
                       const unsigned short* __restrict__ Bt,
                       unsigned short* __restrict__ C, int ldc) {
  __shared__ __align__(16) short As[128 * 32];
  __shared__ __align__(16) short Bs[128 * 32];
  const int tid = threadIdx.x;
  const int id = blockIdx.x;
  int mi, ni;
  if (SWIZ) {
    int t = id >> 3;
    mi = (id & 7) * ((gridDim.x / NTILES) >> 3) + t / NTILES;
    ni = t % NTILES;
  } else {
    mi = id / NTILES; ni = id % NTILES;
  }
  const int m0 = mi * 128, n0 = ni * 128;
  const int lane = tid & 63, wave = tid >> 6;
  const int wm = (wave >> 1) * 64, wn = (wave & 1) * 64;
  const int quad = lane >> 4, mr = lane & 15;
  f32x4 acc[4][4];
#pragma unroll
  for (int i = 0; i < 4; ++i)
#pragma unroll
    for (int j = 0; j < 4; ++j) acc[i][j] = (f32x4){0.f, 0.f, 0.f, 0.f};

  const int r = tid >> 2;
  const int q = (tid & 3) ^ ((r >> 1) & 3);
  const unsigned short* Ar0 = A + (size_t)(m0 + r) * KK + q * 8;
  const unsigned short* Ar1 = A + (size_t)(m0 + 64 + r) * KK + q * 8;
  const unsigned short* Br0 = Bt + (size_t)(n0 + r) * KK + q * 8;
  const unsigned short* Br1 = Bt + (size_t)(n0 + 64 + r) * KK + q * 8;

  int aoff[4], boff[4];
#pragma unroll
  for (int i = 0; i < 4; ++i) {
    int rl = wm + i * 16 + mr;
    aoff[i] = (rl * 4 + (quad ^ ((rl >> 1) & 3))) * 8;
    int nl = wn + i * 16 + mr;
    boff[i] = (nl * 4 + (quad ^ ((nl >> 1) & 3))) * 8;
  }

  for (int k0 = 0; k0 < KK; k0 += 32) {
    __syncthreads();
    gld_lds16(Ar0 + k0, &As[tid * 8]);
    gld_lds16(Ar1 + k0, &As[2048 + tid * 8]);
    gld_lds16(Br0 + k0, &Bs[tid * 8]);
    gld_lds16(Br1 + k0, &Bs[2048 + tid * 8]);
    __syncthreads();
    s16x8 a[4], b[4];
#pragma unroll
    for (int i = 0; i < 4; ++i) a[i] = *(const s16x8*)&As[aoff[i]];
#pragma unroll
    for (int j = 0; j < 4; ++j) b[j] = *(const s16x8*)&Bs[boff[j]];
#pragma unroll
    for (int i = 0; i < 4; ++i)
#pragma unroll
      for (int j = 0; j < 4; ++j)
        acc[i][j] = __builtin_amdgcn_mfma_f32_16x16x32_bf16(a[i], b[j], acc[i][j], 0, 0, 0);
  }
#pragma unroll
  for (int i = 0; i < 4; ++i) {
    int row = m0 + wm + i * 16 + quad * 4;
#pragma unroll
    for (int j = 0; j < 4; ++j) {
      int col = n0 + wn + j * 16 + mr;
#pragma unroll
      for (int t = 0; t < 4; ++t)
        C[(size_t)(row + t) * ldc + col] = f2bf(acc[i][j][t]);
    }
  }
}

// ---- main GEMM, 256x256 tile, BK=32, 4-slot LDS ring, 3 slots in flight.
// ONE barrier per slot:
//   [12 ds_read (bF0-3,aF0-3 ; MFMA 0-3 ; aF4-7 ; MFMA 4-7) | 4 gld_lds -> ring s+3
//    | (harvest x cols for c-dots at 2 slots) | vmcnt(8) | s_barrier ]
// Hazards: reads of slot s published by end-of-(s-1) barrier (vmcnt drained slot s
// loads there); STAGE at slot s targets ring (s-1)&3 whose readers all finished
// before that same barrier (their MFMAs consumed the data).
// c-half blocks (ni>=3) write no C: they harvest x from the A-LDS slots covering
// their 64 columns and produce d11/d12/d21/d22 partials -> atomicAdd dts[4][ROWS].
__launch_bounds__(512, 2)
__global__ void k_gemm256(const unsigned short* __restrict__ A,
                          const unsigned short* __restrict__ Bt,
                          unsigned short* __restrict__ C,
                          const float* __restrict__ gn,
                          float* __restrict__ dts) {
  extern __shared__ __align__(16) short lds[];
  const int tid = threadIdx.x;
  const int id = blockIdx.x;
  const int xcd = id & 7, tt = id >> 3;      // 1536 blocks, 192/XCD, same-m grouped
  const int mi = xcd * 32 + tt / 6;
  const int ni = tt % 6;
  const int m0 = mi * 256, n0 = ni * 256;
  const int lane = tid & 63, wave = tid >> 6;
  const int WM = (wave >> 2) * 128, WN = (wave & 3) * 64;
  const int quad = lane >> 4, mr = lane & 15;

  f32x4 acc[8][4];
#pragma unroll
  for (int i = 0; i < 8; ++i)
#pragma unroll
    for (int j = 0; j < 4; ++j) acc[i][j] = (f32x4){0.f, 0.f, 0.f, 0.f};

  // staging: thread tid -> row r0 = tid>>2 (0..127), lds chunk qt = tid&3;
  // global chunk pre-swizzled: q = qt ^ ((r0>>1)&3). LDS stays linear.
  const int r0 = tid >> 2;
  const int qg = ((tid & 3) ^ ((r0 >> 1) & 3)) * 8;
  const unsigned short* a0 = A + (size_t)(m0 + r0) * D_ + qg;
  const unsigned short* a1 = A + (size_t)(m0 + 128 + r0) * D_ + qg;
  const unsigned short* b0 = Bt + (size_t)(n0 + r0) * D_ + qg;
  const unsigned short* b1 = Bt + (size_t)(n0 + 128 + r0) * D_ + qg;
  const int ld0 = tid * 8;

  // ring slot layout (shorts): slot*16384 + { A[256][4][8] | B at +8192 }
#define STAGE_A(RNG, KT) do { \
    gld_lds16(a0 + (KT) * 32, &lds[(RNG) * 16384 + ld0]); \
    gld_lds16(a1 + (KT) * 32, &lds[(RNG) * 16384 + 4096 + ld0]); } while (0)
#define STAGE_B(RNG, KT) do { \
    gld_lds16(b0 + (KT) * 32, &lds[(RNG) * 16384 + 8192 + ld0]); \
    gld_lds16(b1 + (KT) * 32, &lds[(RNG) * 16384 + 8192 + 4096 + ld0]); } while (0)

  // fragment bases: XOR chunk is invariant across the 16-row fragment step,
  // so reads are base + i*512 shorts (folds into ds_read offset immediates)
  const int chnk = (quad ^ ((mr >> 1) & 3)) * 8;
  const int abase = (WM + mr) * 32 + chnk;
  const int bbase = (WN + mr) * 32 + chnk;

  const bool cHalf = (ni >= 3);
  const int cc0 = n0 - D_;                       // c-half column origin
  const int hs0 = cHalf ? ((cc0 + WN) >> 5) : -9; // first harvest slot (wave-uniform)
  unsigned int hxp[8][4][2];                      // packed bf16 x values (c-half only)

#define DO_H(H_, SBASE_) do { \
  _Pragma("unroll") \
  for (int i_ = 0; i_ < 8; ++i_) { \
    _Pragma("unroll") \
    for (int t_ = 0; t_ < 4; ++t_) { \
      const int rl_ = WM + i_ * 16 + quad * 4 + t_; \
      const int w_ = (rl_ >> 1) & 3; \
      const int base_ = (SBASE_) + rl_ * 32 + (mr & 7); \
      unsigned int v0_ = *(const unsigned short*)&lds[base_ + (((mr >> 3) ^ w_) << 3)]; \
      unsigned int v1_ = *(const unsigned short*)&lds[base_ + ((((mr >> 3) + 2) ^ w_) << 3)]; \
      hxp[i_][t_][H_] = v0_ | (v1_ << 16); \
    } \
  } \
  asm volatile("s_waitcnt lgkmcnt(0)" ::: "memory"); \
} while (0)

#define SLOT_BODY(S_, DOSTAGE_) do { \
  const int sb_ = ((S_) & 3) * 16384; \
  s16x8 aF[4], bF[4]; \
  _Pragma("unroll") \
  for (int j_ = 0; j_ < 4; ++j_) bF[j_] = *(const s16x8*)&lds[sb_ + 8192 + bbase + j_ * 512]; \
  _Pragma("unroll") \
  for (int i_ = 0; i_ < 4; ++i_) aF[i_] = *(const s16x8*)&lds[sb_ + abase + i_ * 512]; \
  if (DOSTAGE_) { STAGE_A(((S_) + 3) & 3, (S_) + 3); STAGE_B(((S_) + 3) & 3, (S_) + 3); } \
  __builtin_amdgcn_s_setprio(1); \
  _Pragma("unroll") \
  for (int i_ = 0; i_ < 4; ++i_) \
    _Pragma("unroll") \
    for (int j_ = 0; j_ < 4; ++j_) \
      acc[i_][j_] = __builtin_amdgcn_mfma_f32_16x16x32_bf16(aF[i_], bF[j_], acc[i_][j_], 0, 0, 0); \
  _Pragma("unroll") \
  for (int i_ = 0; i_ < 4; ++i_) aF[i_] = *(const s16x8*)&lds[sb_ + abase + (4 + i_) * 512]; \
  _Pragma("unroll") \
  for (int i_ = 0; i_ < 4; ++i_) \
    _Pragma("unroll") \
    for (int j_ = 0; j_ < 4; ++j_) \
      acc[4 + i_][j_] = __builtin_amdgcn_mfma_f32_16x16x32_bf16(aF[i_], bF[j_], acc[4 + i_][j_], 0, 0, 0); \
  __builtin_amdgcn_s_setprio(0); \
  if (cHalf) { \
    if ((S_) == hs0) DO_H(0, sb_); \
    else if ((S_) == hs0 + 1) DO_H(1, sb_); \
  } \
} while (0)

  // prologue: stage data slots 0,1,2 into ring 0,1,2; wait slot 0 landed.
  STAGE_A(0, 0); STAGE_B(0, 0);
  STAGE_A(1, 1); STAGE_B(1, 1);
  STAGE_A(2, 2); STAGE_B(2, 2);
  asm volatile("s_waitcnt vmcnt(8)" ::: "memory");
  __builtin_amdgcn_s_barrier();

#pragma unroll 4
  for (int s = 0; s < 20; ++s) {
    SLOT_BODY(s, true);
    asm volatile("s_waitcnt vmcnt(8)" ::: "memory");
    __builtin_amdgcn_s_barrier();
  }
  // tail: slots 20..23 (slot 20 still stages data slot 23)
  SLOT_BODY(20, true);
  asm volatile("s_waitcnt vmcnt(8)" ::: "memory");
  __builtin_amdgcn_s_barrier();
  SLOT_BODY(21, false);
  asm volatile("s_waitcnt vmcnt(4)" ::: "memory");
  __builtin_amdgcn_s_barrier();
  SLOT_BODY(22, false);
  asm volatile("s_waitcnt vmcnt(0)" ::: "memory");
  __builtin_amdgcn_s_barrier();
  SLOT_BODY(23, false);

#undef SLOT_BODY
#undef DO_H
#undef STAGE_A
#undef STAGE_B

  if (!cHalf) {
    // v-half epilogue: write vc (ldc = 768)
#pragma unroll
    for (int i = 0; i < 8; ++i) {
      const int row = m0 + WM + i * 16 + quad * 4;
#pragma unroll
      for (int j = 0; j < 4; ++j) {
        const int col = n0 + WN + j * 16 + mr;
#pragma unroll
        for (int v = 0; v < 4; ++v)
          C[(size_t)(row + v) * D_ + col] = f2bf(acc[i][j][v]);
      }
    }
  } else {
    // c-half epilogue: dots from harvested x (bf16-packed in hxp)
#pragma unroll
    for (int i = 0; i < 8; ++i) {
      const int rb = m0 + WM + i * 16 + quad * 4;   // even row (pairs rb/2, rb/2+1)
      float d[2][4];
#pragma unroll
      for (int tp = 0; tp < 2; ++tp)
#pragma unroll
        for (int k = 0; k < 4; ++k) d[tp][k] = 0.f;
#pragma unroll
      for (int j = 0; j < 4; ++j) {
        const int cc = cc0 + WN + j * 16 + mr;
        const float gvj = gn[cc];
#pragma unroll
        for (int tp = 0; tp < 2; ++tp) {
          const float c1 = acc[i][j][tp * 2], c2 = acc[i][j][tp * 2 + 1];
          const float a1v = bf2f((unsigned short)(hxp[i][tp * 2][j >> 1] >> ((j & 1) * 16)));
          const float a2v = bf2f((unsigned short)(hxp[i][tp * 2 + 1][j >> 1] >> ((j & 1) * 16)));
          d[tp][0] += a1v * (c1 + gvj);
          d[tp][1] += a1v * c2;
          d[tp][2] += a2v * c1;
          d[tp][3] += a2v * (c2 + gvj);
        }
      }
#pragma unroll
      for (int m = 1; m < 16; m <<= 1)
#pragma unroll
        for (int tp = 0; tp < 2; ++tp)
#pragma unroll
          for (int k = 0; k < 4; ++k)
            d[tp][k] += __shfl_xor(d[tp][k], m, 64);
      if (mr == 0) {
#pragma unroll
        for (int tp = 0; tp < 2; ++tp) {
          const int p = (rb >> 1) + tp;
#pragma unroll
          for (int k = 0; k < 4; ++k)
            atomicAdd(&dts[(size_t)k * ROWS + p], d[tp][k]);
        }
      }
    }
  }
}

// ---- MLP GEMM (both directions fused): A = xb viewed [32768,1536], Bt = BtMlp [384,1536]
__launch_bounds__(256)
__global__ void k_gemm_mlp(const unsigned short* __restrict__ A,
                           const unsigned short* __restrict__ Bt,
                           const float* __restrict__ b1, const float* __restrict__ W2,
                           float* __restrict__ rel) {
  __shared__ __align__(16) short As[128 * 32];
  __shared__ __align__(16) short Bs[128 * 32];
  const int tid = threadIdx.x;
  const int id = blockIdx.x;            // 768 blocks
  int t0 = id >> 3;
  const int mi = (id & 7) * 32 + t0 / 3;
  const int ni = t0 % 3;
  const int m0 = mi * 128, n0 = ni * 128;
  const int lane = tid & 63, wave = tid >> 6;
  const int wm = (wave >> 1) * 64, wn = (wave & 1) * 64;
  const int quad = lane >> 4, mr = lane & 15;
  f32x4 acc[4][4];
#pragma unroll
  for (int i = 0; i < 4; ++i)
#pragma unroll
    for (int j = 0; j < 4; ++j) acc[i][j] = (f32x4){0.f, 0.f, 0.f, 0.f};

  const int r = tid >> 2;
  const int q = (tid & 3) ^ ((r >> 1) & 3);
  const unsigned short* Ar0 = A + (size_t)(m0 + r) * KMLP + q * 8;
  const unsigned short* Ar1 = A + (size_t)(m0 + 64 + r) * KMLP + q * 8;
  const unsigned short* Br0 = Bt + (size_t)(n0 + r) * KMLP + q * 8;
  const unsigned short* Br1 = Bt + (size_t)(n0 + 64 + r) * KMLP + q * 8;
  int aoff[4], boff[4];
#pragma unroll
  for (int i = 0; i < 4; ++i) {
    int rl = wm + i * 16 + mr;
    aoff[i] = (rl * 4 + (quad ^ ((rl >> 1) & 3))) * 8;
    int nl = wn + i * 16 + mr;
    boff[i] = (nl * 4 + (quad ^ ((nl >> 1) & 3))) * 8;
  }
  for (int k0 = 0; k0 < KMLP; k0 += 32) {
    __syncthreads();
    gld_lds16(Ar0 + k0, &As[tid * 8]);
    gld_lds16(Ar1 + k0, &As[2048 + tid * 8]);
    gld_lds16(Br0 + k0, &Bs[tid * 8]);
    gld_lds16(Br1 + k0, &Bs[2048 + tid * 8]);
    __syncthreads();
    s16x8 a[4], b[4];
#pragma unroll
    for (int i = 0; i < 4; ++i) a[i] = *(const s16x8*)&As[aoff[i]];
#pragma unroll
    for (int j = 0; j < 4; ++j) b[j] = *(const s16x8*)&Bs[boff[j]];
#pragma unroll
    for (int i = 0; i < 4; ++i)
#pragma unroll
      for (int j = 0; j < 4; ++j)
        acc[i][j] = __builtin_amdgcn_mfma_f32_16x16x32_bf16(a[i], b[j], acc[i][j], 0, 0, 0);
  }
  float part[2][4][4];
#pragma unroll
  for (int d = 0; d < 2; ++d)
#pragma unroll
    for (int i = 0; i < 4; ++i)
#pragma unroll
      for (int t = 0; t < 4; ++t) part[d][i][t] = 0.f;
#pragma unroll
  for (int j = 0; j < 4; ++j) {
    const int colb = n0 + wn + j * 16;        // wave-uniform
    const int dir = (colb >= HID) ? 1 : 0;
    const int cc = colb + mr - dir * HID;     // 0..191
    const float b1v = b1[cc];
    const float w2v = W2[cc];
#pragma unroll
    for (int i = 0; i < 4; ++i)
#pragma unroll
      for (int t = 0; t < 4; ++t) {
        float h = acc[i][j][t] + b1v;
        h = 0.5f * h * (1.f + erff(h * 0.70710678118654752f));
        part[dir][i][t] += h * w2v;
      }
  }
#pragma unroll
  for (int m = 1; m < 16; m <<= 1)
#pragma unroll
    for (int d = 0; d < 2; ++d)
#pragma unroll
      for (int i = 0; i < 4; ++i)
#pragma unroll
        for (int t = 0; t < 4; ++t)
          part[d][i][t] += __shfl_xor(part[d][i][t], m, 64);
  if (mr == 0) {
#pragma unroll
    for (int d = 0; d < 2; ++d)
#pragma unroll
      for (int i = 0; i < 4; ++i) {
        int p = m0 + wm + i * 16 + quad * 4;
#pragma unroll
        for (int t = 0; t < 4; ++t)
          atomicAdd(&rel[(size_t)d * ROWS + p + t], part[d][i][t]);
      }
  }
}

// ---- fusion: one wave per row-pair (dots precomputed by k_gemm256)
__launch_bounds__(256)
__global__ void k_fuse(const float* __restrict__ x1, const float* __restrict__ x2,
                       const unsigned short* __restrict__ vc,
                       const float* __restrict__ dts, const float* __restrict__ rel,
                       const float* __restrict__ b2, float* __restrict__ y) {
  const int p = blockIdx.x * 4 + (threadIdx.x >> 6);
  const int lane = threadIdx.x & 63;
  const unsigned short* L1 = vc + (size_t)(2 * p) * D_;
  const unsigned short* L2 = L1 + D_;
  const float* X1 = x1 + (size_t)p * D_;
  const float* X2 = x2 + (size_t)p * D_;
  const float scale = 0.0360843918243516f;   // 768^-0.5
  const float b2v = b2[0];
  const float d11 = dts[p], d12 = dts[ROWS + p];
  const float d21 = dts[2 * ROWS + p], d22 = dts[3 * ROWS + p];
  const float r1 = 1.f / (1.f + expf(-(rel[p] + b2v)));
  const float r2 = 1.f / (1.f + expf(-(rel[ROWS + p] + b2v)));
  const float ds1 = d11 * scale, dc1 = r1 * d12 * scale;
  const float ds2 = d22 * scale, dc2 = r2 * d21 * scale;
  const float ws1 = 1.f / (1.f + expf(dc1 - ds1)), wc1 = 1.f - ws1;
  const float ws2 = 1.f / (1.f + expf(dc2 - ds2)), wc2 = 1.f - ws2;
  float* Y1 = y + (size_t)p * D_;
  float* Y2 = y + (size_t)(ROWS + p) * D_;
  for (int c = lane; c < 96; c += 64) {
    const int off = c * 8;
    s16x8 v1 = *(const s16x8*)(L1 + off);
    s16x8 v2 = *(const s16x8*)(L2 + off);
    union F8 { float4 v[2]; float f[8]; };
    F8 a1, a2, o1, o2;
    a1.v[0] = *(const float4*)(X1 + off); a1.v[1] = *(const float4*)(X1 + off + 4);
    a2.v[0] = *(const float4*)(X2 + off); a2.v[1] = *(const float4*)(X2 + off + 4);
#pragma unroll
    for (int e = 0; e < 8; ++e) {
      float fv1 = bf2f(v1[e]), fv2 = bf2f(v2[e]);
      o1.f[e] = a1.f[e] + ws1 * fv1 + wc1 * fv2;
      o2.f[e] = a2.f[e] + ws2 * fv2 + wc2 * fv1;
    }
    *(float4*)(Y1 + off) = o1.v[0]; *(float4*)(Y1 + off + 4) = o1.v[1];
    *(float4*)(Y2 + off) = o2.v[0]; *(float4*)(Y2 + off + 4) = o2.v[1];
  }
}

extern "C" void kernel_launch(void* const* d_in, const int* in_sizes, int n_in,
                              void* d_out, int out_size, void* d_ws, size_t ws_size,
                              hipStream_t stream) {
  const float* x1 = (const float*)d_in[0];
  const float* x2 = (const float*)d_in[1];
  const float* Wq = (const float*)d_in[2];
  const float* Wk = (const float*)d_in[3];
  const float* Wv = (const float*)d_in[4];
  const float* noise = (const float*)d_in[5];
  const float* W1 = (const float*)d_in[6];
  const float* b1 = (const float*)d_in[7];
  const float* W2 = (const float*)d_in[8];
  const float* b2 = (const float*)d_in[9];
  float* y = (float*)d_out;

  char* ws = (char*)d_ws;
  size_t off = 0;
  auto alloc = [&](size_t bytes) {
    char* p = ws + off;
    off += (bytes + 255) & ~(size_t)255;
    return p;
  };
  unsigned short* xb     = (unsigned short*)alloc((size_t)MTOT * D_ * 2);       // 100.7 MB
  unsigned short* vc     = (unsigned short*)alloc((size_t)MTOT * D_ * 2);       // 100.7 MB (v-half only)
  unsigned short* BtMain = (unsigned short*)alloc((size_t)2 * D_ * D_ * 2);     // [Wv^T | G]
  unsigned short* Wqb    = (unsigned short*)alloc((size_t)D_ * D_ * 2);
  unsigned short* Wkb    = (unsigned short*)alloc((size_t)D_ * D_ * 2);
  unsigned short* BtMlp  = (unsigned short*)alloc((size_t)NMLP * KMLP * 2);
  float* nk              = (float*)alloc((size_t)D_ * 4);
  float* gn              = (float*)alloc((size_t)D_ * 4);
  float* rel             = (float*)alloc((size_t)2 * ROWS * 4);
  float* dts             = (float*)alloc((size_t)4 * ROWS * 4);

  static bool attr_set = false;
  if (!attr_set) {
    (void)hipFuncSetAttribute((const void*)k_gemm256,
                              hipFuncAttributeMaxDynamicSharedMemorySize, 131072);
    attr_set = true;
  }

  hipMemsetAsync(rel, 0, (size_t)2 * ROWS * 4, stream);
  hipMemsetAsync(dts, 0, (size_t)4 * ROWS * 4, stream);

  k_convert_x<<<dim3(MTOT), 192, 0, stream>>>(x1, x2, xb);

  {
    int total = 3 * D_ * D_ + NMLP * KMLP;
    k_convert_w<<<dim3((total + 255) / 256), 256, 0, stream>>>(Wq, Wk, Wv, W1,
                                                               Wqb, Wkb, BtMain, BtMlp);
  }
  k_nk<<<dim3(3), 256, 0, stream>>>(noise, Wk, nk);
  k_gn<<<dim3(3), 256, 0, stream>>>(Wq, nk, gn);

  // G = Wq @ Wk^T (bf16) -> BtMain rows 768..1535
  k_gemm<6, false, D_><<<dim3(36), 256, 0, stream>>>(Wqb, Wkb, BtMain + (size_t)D_ * D_, D_);

  // main: v-half -> vc writes; c-half -> in-loop harvest + dots
  k_gemm256<<<dim3(1536), 512, 131072, stream>>>(xb, BtMain, vc, gn, dts);

  // MLP both dirs: rel logits
  k_gemm_mlp<<<dim3(768), 256, 0, stream>>>(xb, BtMlp, b1, W2, rel);

  // fusion
  k_fuse<<<dim3(ROWS / 4), 256, 0, stream>>>(x1, x2, vc, dts, rel, b2, y);
}

// Round 4
// 808.942 us; speedup vs baseline: 1.5924x; 1.5924x over previous
//
#include <hip/hip_runtime.h>
#include <cstdint>
#include <cstddef>

#define D_    768
#define ROWS  32768      // row pairs (B*N)
#define MTOT  65536      // interleaved rows: 2i = x1_i, 2i+1 = x2_i
#define HID   192
#define KMLP  1536
#define NMLP  384

typedef __attribute__((ext_vector_type(4))) float f32x4;
typedef __attribute__((ext_vector_type(8))) short s16x8;

__device__ inline unsigned short f2bf(float f) {
  union { float f; uint32_t u; } c; c.f = f;
  uint32_t r = c.u + 0x7FFFu + ((c.u >> 16) & 1u);
  return (unsigned short)(r >> 16);
}
__device__ inline float bf2f(unsigned short h) {
  union { uint32_t u; float f; } c; c.u = ((uint32_t)h) << 16;
  return c.f;
}

__device__ inline void gld_lds16(const void* g, void* l) {
  __builtin_amdgcn_global_load_lds(
      (const __attribute__((address_space(1))) void*)g,
      (__attribute__((address_space(3))) void*)l, 16, 0, 0);
}

// ---- x1,x2 fp32 -> xb bf16, pair-interleaved [65536, 768]
__global__ void k_convert_x(const float* __restrict__ x1, const float* __restrict__ x2,
                            unsigned short* __restrict__ xb) {
  const int r = blockIdx.x;               // output row
  const int c = threadIdx.x * 4;
  const float* src = ((r & 1) ? x2 : x1) + (size_t)(r >> 1) * D_ + c;
  float4 v = *(const float4*)src;
  union { unsigned short u[4]; uint2 p; } o;
  o.u[0] = f2bf(v.x); o.u[1] = f2bf(v.y); o.u[2] = f2bf(v.z); o.u[3] = f2bf(v.w);
  *(uint2*)(xb + (size_t)r * D_ + c) = o.p;
}

// ---- weight conversions
__global__ void k_convert_w(const float* __restrict__ Wq, const float* __restrict__ Wk,
                            const float* __restrict__ Wv, const float* __restrict__ W1,
                            unsigned short* __restrict__ Wqb, unsigned short* __restrict__ Wkb,
                            unsigned short* __restrict__ BtMain, unsigned short* __restrict__ BtMlp) {
  int idx = blockIdx.x * 256 + threadIdx.x;
  const int S = D_ * D_;
  if (idx < S) { Wqb[idx] = f2bf(Wq[idx]); return; }
  idx -= S;
  if (idx < S) { Wkb[idx] = f2bf(Wk[idx]); return; }
  idx -= S;
  if (idx < S) {
    int n = idx / D_, k = idx - n * D_;
    BtMain[idx] = f2bf(Wv[(size_t)k * D_ + n]);
    return;
  }
  idx -= S;
  if (idx < NMLP * KMLP) {
    int n = idx / KMLP, k = idx - n * KMLP;
    int cc = (n < HID) ? n : n - HID;
    int kk = (n < HID) ? k : ((k < D_) ? k + D_ : k - D_);
    BtMlp[idx] = f2bf(W1[(size_t)kk * HID + cc]);
  }
}

// ---- nk[j] = noise @ Wk ;  gn[a] = Wq[a][:] . nk  (fp32 throughout)
__global__ void k_nk(const float* __restrict__ noise, const float* __restrict__ Wk,
                     float* __restrict__ nk) {
  int j = blockIdx.x * 256 + threadIdx.x;
  if (j >= D_) return;
  float s = 0.f;
  for (int k = 0; k < D_; ++k) s += noise[k] * Wk[(size_t)k * D_ + j];
  nk[j] = s;
}
__global__ void k_gn(const float* __restrict__ Wq, const float* __restrict__ nk,
                     float* __restrict__ gn) {
  int a = blockIdx.x * 256 + threadIdx.x;
  if (a >= D_) return;
  float s = 0.f;
  for (int j = 0; j < D_; ++j) s += Wq[(size_t)a * D_ + j] * nk[j];
  gn[a] = s;
}

// ---- generic 128x128 bf16 GEMM (kept for the small G = Wq@Wk^T gemm)
template<int NTILES, bool SWIZ, int KK>
__launch_bounds__(256)
__global__ void k_gemm(const unsigned short* __restrict__ A,
                       const unsigned short* __restrict__ Bt,
                       unsigned short* __restrict__ C, int ldc) {
  __shared__ __align__(16) short As[128 * 32];
  __shared__ __align__(16) short Bs[128 * 32];
  const int tid = threadIdx.x;
  const int id = blockIdx.x;
  int mi, ni;
  if (SWIZ) {
    int t = id >> 3;
    mi = (id & 7) * ((gridDim.x / NTILES) >> 3) + t / NTILES;
    ni = t % NTILES;
  } else {
    mi = id / NTILES; ni = id % NTILES;
  }
  const int m0 = mi * 128, n0 = ni * 128;
  const int lane = tid & 63, wave = tid >> 6;
  const int wm = (wave >> 1) * 64, wn = (wave & 1) * 64;
  const int quad = lane >> 4, mr = lane & 15;
  f32x4 acc[4][4];
#pragma unroll
  for (int i = 0; i < 4; ++i)
#pragma unroll
    for (int j = 0; j < 4; ++j) acc[i][j] = (f32x4){0.f, 0.f, 0.f, 0.f};

  const int r = tid >> 2;
  const int q = (tid & 3) ^ ((r >> 1) & 3);
  const unsigned short* Ar0 = A + (size_t)(m0 + r) * KK + q * 8;
  const unsigned short* Ar1 = A + (size_t)(m0 + 64 + r) * KK + q * 8;
  const unsigned short* Br0 = Bt + (size_t)(n0 + r) * KK + q * 8;
  const unsigned short* Br1 = Bt + (size_t)(n0 + 64 + r) * KK + q * 8;

  int aoff[4], boff[4];
#pragma unroll
  for (int i = 0; i < 4; ++i) {
    int rl = wm + i * 16 + mr;
    aoff[i] = (rl * 4 + (quad ^ ((rl >> 1) & 3))) * 8;
    int nl = wn + i * 16 + mr;
    boff[i] = (nl * 4 + (quad ^ ((nl >> 1) & 3))) * 8;
  }

  for (int k0 = 0; k0 < KK; k0 += 32) {
    __syncthreads();
    gld_lds16(Ar0 + k0, &As[tid * 8]);
    gld_lds16(Ar1 + k0, &As[2048 + tid * 8]);
    gld_lds16(Br0 + k0, &Bs[tid * 8]);
    gld_lds16(Br1 + k0, &Bs[2048 + tid * 8]);
    __syncthreads();
    s16x8 a[4], b[4];
#pragma unroll
    for (int i = 0; i < 4; ++i) a[i] = *(const s16x8*)&As[aoff[i]];
#pragma unroll
    for (int j = 0; j < 4; ++j) b[j] = *(const s16x8*)&Bs[boff[j]];
#pragma unroll
    for (int i = 0; i < 4; ++i)
#pragma unroll
      for (int j = 0; j < 4; ++j)
        acc[i][j] = __builtin_amdgcn_mfma_f32_16x16x32_bf16(a[i], b[j], acc[i][j], 0, 0, 0);
  }
#pragma unroll
  for (int i = 0; i < 4; ++i) {
    int row = m0 + wm + i * 16 + quad * 4;
#pragma unroll
    for (int j = 0; j < 4; ++j) {
      int col = n0 + wn + j * 16 + mr;
#pragma unroll
      for (int t = 0; t < 4; ++t)
        C[(size_t)(row + t) * ldc + col] = f2bf(acc[i][j][t]);
    }
  }
}

// ---- main GEMM, 256x256 tile, BK=32, 4-slot LDS ring, 3 slots in flight.
// ONE barrier per slot:
//   [12 ds_read | 4 gld_lds -> ring (s+3)&3 | MFMA x32 | vmcnt(8) | s_barrier]
// Hazards: reads of slot s published by end-of-(s-1) barrier (vmcnt there drains
// slot-s loads); STAGE in slot s targets ring (s-1)&3, whose ds_reads were all
// consumed (registers) before the preceding barrier. Schedule verified in r3.
// NO harvest (r3 lesson: +64 live VGPRs -> unified-file spill, 1.1 GB scratch).
// c-half blocks (ni>=3): no C write; dots via global x re-read in epilogue.
__launch_bounds__(512, 2)
__global__ void k_gemm256(const unsigned short* __restrict__ A,
                          const unsigned short* __restrict__ Bt,
                          unsigned short* __restrict__ C,
                          const float* __restrict__ gn,
                          float* __restrict__ dts) {
  extern __shared__ __align__(16) short lds[];
  const int tid = threadIdx.x;
  const int id = blockIdx.x;
  const int xcd = id & 7, tt = id >> 3;      // 1536 blocks, 192/XCD, same-m grouped
  const int mi = xcd * 32 + tt / 6;
  const int ni = tt % 6;
  const int m0 = mi * 256, n0 = ni * 256;
  const int lane = tid & 63, wave = tid >> 6;
  const int WM = (wave >> 2) * 128, WN = (wave & 3) * 64;
  const int quad = lane >> 4, mr = lane & 15;

  f32x4 acc[8][4];
#pragma unroll
  for (int i = 0; i < 8; ++i)
#pragma unroll
    for (int j = 0; j < 4; ++j) acc[i][j] = (f32x4){0.f, 0.f, 0.f, 0.f};

  // staging: thread tid -> row r0 = tid>>2 (0..127), lds chunk qt = tid&3;
  // global chunk pre-swizzled: q = qt ^ ((r0>>1)&3). LDS stays linear.
  const int r0 = tid >> 2;
  const int qg = ((tid & 3) ^ ((r0 >> 1) & 3)) * 8;
  const unsigned short* a0 = A + (size_t)(m0 + r0) * D_ + qg;
  const unsigned short* a1 = A + (size_t)(m0 + 128 + r0) * D_ + qg;
  const unsigned short* b0 = Bt + (size_t)(n0 + r0) * D_ + qg;
  const unsigned short* b1 = Bt + (size_t)(n0 + 128 + r0) * D_ + qg;
  const int ld0 = tid * 8;

  // ring slot layout (shorts): slot*16384 + { A[256][4][8] | B at +8192 }
#define STAGE_A(RNG, KT) do { \
    gld_lds16(a0 + (KT) * 32, &lds[(RNG) * 16384 + ld0]); \
    gld_lds16(a1 + (KT) * 32, &lds[(RNG) * 16384 + 4096 + ld0]); } while (0)
#define STAGE_B(RNG, KT) do { \
    gld_lds16(b0 + (KT) * 32, &lds[(RNG) * 16384 + 8192 + ld0]); \
    gld_lds16(b1 + (KT) * 32, &lds[(RNG) * 16384 + 8192 + 4096 + ld0]); } while (0)

  // fragment bases: XOR chunk invariant across the 16-row fragment step,
  // so reads are base + i*512 shorts (folds into ds_read offset immediates)
  const int chnk = (quad ^ ((mr >> 1) & 3)) * 8;
  const int abase = (WM + mr) * 32 + chnk;
  const int bbase = (WN + mr) * 32 + chnk;

  const bool cHalf = (ni >= 3);
  const int cc0 = n0 - D_;                       // c-half column origin

#define SLOT_BODY(S_, DOSTAGE_) do { \
  const int sb_ = ((S_) & 3) * 16384; \
  s16x8 aF[4], bF[4]; \
  _Pragma("unroll") \
  for (int j_ = 0; j_ < 4; ++j_) bF[j_] = *(const s16x8*)&lds[sb_ + 8192 + bbase + j_ * 512]; \
  _Pragma("unroll") \
  for (int i_ = 0; i_ < 4; ++i_) aF[i_] = *(const s16x8*)&lds[sb_ + abase + i_ * 512]; \
  if (DOSTAGE_) { STAGE_A(((S_) + 3) & 3, (S_) + 3); STAGE_B(((S_) + 3) & 3, (S_) + 3); } \
  __builtin_amdgcn_s_setprio(1); \
  _Pragma("unroll") \
  for (int i_ = 0; i_ < 4; ++i_) \
    _Pragma("unroll") \
    for (int j_ = 0; j_ < 4; ++j_) \
      acc[i_][j_] = __builtin_amdgcn_mfma_f32_16x16x32_bf16(aF[i_], bF[j_], acc[i_][j_], 0, 0, 0); \
  _Pragma("unroll") \
  for (int i_ = 0; i_ < 4; ++i_) aF[i_] = *(const s16x8*)&lds[sb_ + abase + (4 + i_) * 512]; \
  _Pragma("unroll") \
  for (int i_ = 0; i_ < 4; ++i_) \
    _Pragma("unroll") \
    for (int j_ = 0; j_ < 4; ++j_) \
      acc[4 + i_][j_] = __builtin_amdgcn_mfma_f32_16x16x32_bf16(aF[i_], bF[j_], acc[4 + i_][j_], 0, 0, 0); \
  __builtin_amdgcn_s_setprio(0); \
} while (0)

  // prologue: stage data slots 0,1,2 into ring 0,1,2; wait slot 0 landed.
  STAGE_A(0, 0); STAGE_B(0, 0);
  STAGE_A(1, 1); STAGE_B(1, 1);
  STAGE_A(2, 2); STAGE_B(2, 2);
  asm volatile("s_waitcnt vmcnt(8)" ::: "memory");
  __builtin_amdgcn_s_barrier();

#pragma unroll 4
  for (int s = 0; s < 20; ++s) {
    SLOT_BODY(s, true);
    asm volatile("s_waitcnt vmcnt(8)" ::: "memory");
    __builtin_amdgcn_s_barrier();
  }
  // tail: slots 20..23 (slot 20 still stages data slot 23)
  SLOT_BODY(20, true);
  asm volatile("s_waitcnt vmcnt(8)" ::: "memory");
  __builtin_amdgcn_s_barrier();
  SLOT_BODY(21, false);
  asm volatile("s_waitcnt vmcnt(4)" ::: "memory");
  __builtin_amdgcn_s_barrier();
  SLOT_BODY(22, false);
  asm volatile("s_waitcnt vmcnt(0)" ::: "memory");
  __builtin_amdgcn_s_barrier();
  SLOT_BODY(23, false);

#undef SLOT_BODY
#undef STAGE_A
#undef STAGE_B

  if (!cHalf) {
    // v-half epilogue: write vc (ldc = 768)
#pragma unroll
    for (int i = 0; i < 8; ++i) {
      const int row = m0 + WM + i * 16 + quad * 4;
#pragma unroll
      for (int j = 0; j < 4; ++j) {
        const int col = n0 + WN + j * 16 + mr;
#pragma unroll
        for (int v = 0; v < 4; ++v)
          C[(size_t)(row + v) * D_ + col] = f2bf(acc[i][j][v]);
      }
    }
  } else {
    // c-half epilogue: partial dots via global x re-read (transient regs only)
#pragma unroll
    for (int i = 0; i < 8; ++i) {
      const int rb = m0 + WM + i * 16 + quad * 4;   // even row (pairs rb/2, rb/2+1)
      float xv[4][4], gv[4];
#pragma unroll
      for (int j = 0; j < 4; ++j) {
        const int cc = cc0 + WN + j * 16 + mr;
        gv[j] = gn[cc];
#pragma unroll
        for (int t = 0; t < 4; ++t)
          xv[t][j] = bf2f(A[(size_t)(rb + t) * D_ + cc]);
      }
      float d[2][4];
#pragma unroll
      for (int tp = 0; tp < 2; ++tp)
#pragma unroll
        for (int k = 0; k < 4; ++k) d[tp][k] = 0.f;
#pragma unroll
      for (int tp = 0; tp < 2; ++tp)
#pragma unroll
        for (int j = 0; j < 4; ++j) {
          const float c1 = acc[i][j][tp * 2], c2 = acc[i][j][tp * 2 + 1];
          const float a1v = xv[tp * 2][j], a2v = xv[tp * 2 + 1][j];
          d[tp][0] += a1v * (c1 + gv[j]);
          d[tp][1] += a1v * c2;
          d[tp][2] += a2v * c1;
          d[tp][3] += a2v * (c2 + gv[j]);
        }
#pragma unroll
      for (int m = 1; m < 16; m <<= 1)
#pragma unroll
        for (int tp = 0; tp < 2; ++tp)
#pragma unroll
          for (int k = 0; k < 4; ++k)
            d[tp][k] += __shfl_xor(d[tp][k], m, 64);
      if (mr == 0) {
#pragma unroll
        for (int tp = 0; tp < 2; ++tp) {
          const int p = (rb >> 1) + tp;
#pragma unroll
          for (int k = 0; k < 4; ++k)
            atomicAdd(&dts[(size_t)k * ROWS + p], d[tp][k]);
        }
      }
    }
  }
}

// ---- MLP GEMM (both directions fused): A = xb viewed [32768,1536], Bt = BtMlp [384,1536]
__launch_bounds__(256)
__global__ void k_gemm_mlp(const unsigned short* __restrict__ A,
                           const unsigned short* __restrict__ Bt,
                           const float* __restrict__ b1, const float* __restrict__ W2,
                           float* __restrict__ rel) {
  __shared__ __align__(16) short As[128 * 32];
  __shared__ __align__(16) short Bs[128 * 32];
  const int tid = threadIdx.x;
  const int id = blockIdx.x;            // 768 blocks
  int t0 = id >> 3;
  const int mi = (id & 7) * 32 + t0 / 3;
  const int ni = t0 % 3;
  const int m0 = mi * 128, n0 = ni * 128;
  const int lane = tid & 63, wave = tid >> 6;
  const int wm = (wave >> 1) * 64, wn = (wave & 1) * 64;
  const int quad = lane >> 4, mr = lane & 15;
  f32x4 acc[4][4];
#pragma unroll
  for (int i = 0; i < 4; ++i)
#pragma unroll
    for (int j = 0; j < 4; ++j) acc[i][j] = (f32x4){0.f, 0.f, 0.f, 0.f};

  const int r = tid >> 2;
  const int q = (tid & 3) ^ ((r >> 1) & 3);
  const unsigned short* Ar0 = A + (size_t)(m0 + r) * KMLP + q * 8;
  const unsigned short* Ar1 = A + (size_t)(m0 + 64 + r) * KMLP + q * 8;
  const unsigned short* Br0 = Bt + (size_t)(n0 + r) * KMLP + q * 8;
  const unsigned short* Br1 = Bt + (size_t)(n0 + 64 + r) * KMLP + q * 8;
  int aoff[4], boff[4];
#pragma unroll
  for (int i = 0; i < 4; ++i) {
    int rl = wm + i * 16 + mr;
    aoff[i] = (rl * 4 + (quad ^ ((rl >> 1) & 3))) * 8;
    int nl = wn + i * 16 + mr;
    boff[i] = (nl * 4 + (quad ^ ((nl >> 1) & 3))) * 8;
  }
  for (int k0 = 0; k0 < KMLP; k0 += 32) {
    __syncthreads();
    gld_lds16(Ar0 + k0, &As[tid * 8]);
    gld_lds16(Ar1 + k0, &As[2048 + tid * 8]);
    gld_lds16(Br0 + k0, &Bs[tid * 8]);
    gld_lds16(Br1 + k0, &Bs[2048 + tid * 8]);
    __syncthreads();
    s16x8 a[4], b[4];
#pragma unroll
    for (int i = 0; i < 4; ++i) a[i] = *(const s16x8*)&As[aoff[i]];
#pragma unroll
    for (int j = 0; j < 4; ++j) b[j] = *(const s16x8*)&Bs[boff[j]];
#pragma unroll
    for (int i = 0; i < 4; ++i)
#pragma unroll
      for (int j = 0; j < 4; ++j)
        acc[i][j] = __builtin_amdgcn_mfma_f32_16x16x32_bf16(a[i], b[j], acc[i][j], 0, 0, 0);
  }
  float part[2][4][4];
#pragma unroll
  for (int d = 0; d < 2; ++d)
#pragma unroll
    for (int i = 0; i < 4; ++i)
#pragma unroll
      for (int t = 0; t < 4; ++t) part[d][i][t] = 0.f;
#pragma unroll
  for (int j = 0; j < 4; ++j) {
    const int colb = n0 + wn + j * 16;        // wave-uniform
    const int dir = (colb >= HID) ? 1 : 0;
    const int cc = colb + mr - dir * HID;     // 0..191
    const float b1v = b1[cc];
    const float w2v = W2[cc];
#pragma unroll
    for (int i = 0; i < 4; ++i)
#pragma unroll
      for (int t = 0; t < 4; ++t) {
        float h = acc[i][j][t] + b1v;
        h = 0.5f * h * (1.f + erff(h * 0.70710678118654752f));
        part[dir][i][t] += h * w2v;
      }
  }
#pragma unroll
  for (int m = 1; m < 16; m <<= 1)
#pragma unroll
    for (int d = 0; d < 2; ++d)
#pragma unroll
      for (int i = 0; i < 4; ++i)
#pragma unroll
        for (int t = 0; t < 4; ++t)
          part[d][i][t] += __shfl_xor(part[d][i][t], m, 64);
  if (mr == 0) {
#pragma unroll
    for (int d = 0; d < 2; ++d)
#pragma unroll
      for (int i = 0; i < 4; ++i) {
        int p = m0 + wm + i * 16 + quad * 4;
#pragma unroll
        for (int t = 0; t < 4; ++t)
          atomicAdd(&rel[(size_t)d * ROWS + p + t], part[d][i][t]);
      }
  }
}

// ---- fusion: one wave per row-pair (dots precomputed by k_gemm256)
__launch_bounds__(256)
__global__ void k_fuse(const float* __restrict__ x1, const float* __restrict__ x2,
                       const unsigned short* __restrict__ vc,
                       const float* __restrict__ dts, const float* __restrict__ rel,
                       const float* __restrict__ b2, float* __restrict__ y) {
  const int p = blockIdx.x * 4 + (threadIdx.x >> 6);
  const int lane = threadIdx.x & 63;
  const unsigned short* L1 = vc + (size_t)(2 * p) * D_;
  const unsigned short* L2 = L1 + D_;
  const float* X1 = x1 + (size_t)p * D_;
  const float* X2 = x2 + (size_t)p * D_;
  const float scale = 0.0360843918243516f;   // 768^-0.5
  const float b2v = b2[0];
  const float d11 = dts[p], d12 = dts[ROWS + p];
  const float d21 = dts[2 * ROWS + p], d22 = dts[3 * ROWS + p];
  const float r1 = 1.f / (1.f + expf(-(rel[p] + b2v)));
  const float r2 = 1.f / (1.f + expf(-(rel[ROWS + p] + b2v)));
  const float ds1 = d11 * scale, dc1 = r1 * d12 * scale;
  const float ds2 = d22 * scale, dc2 = r2 * d21 * scale;
  const float ws1 = 1.f / (1.f + expf(dc1 - ds1)), wc1 = 1.f - ws1;
  const float ws2 = 1.f / (1.f + expf(dc2 - ds2)), wc2 = 1.f - ws2;
  float* Y1 = y + (size_t)p * D_;
  float* Y2 = y + (size_t)(ROWS + p) * D_;
  for (int c = lane; c < 96; c += 64) {
    const int off = c * 8;
    s16x8 v1 = *(const s16x8*)(L1 + off);
    s16x8 v2 = *(const s16x8*)(L2 + off);
    union F8 { float4 v[2]; float f[8]; };
    F8 a1, a2, o1, o2;
    a1.v[0] = *(const float4*)(X1 + off); a1.v[1] = *(const float4*)(X1 + off + 4);
    a2.v[0] = *(const float4*)(X2 + off); a2.v[1] = *(const float4*)(X2 + off + 4);
#pragma unroll
    for (int e = 0; e < 8; ++e) {
      float fv1 = bf2f(v1[e]), fv2 = bf2f(v2[e]);
      o1.f[e] = a1.f[e] + ws1 * fv1 + wc1 * fv2;
      o2.f[e] = a2.f[e] + ws2 * fv2 + wc2 * fv1;
    }
    *(float4*)(Y1 + off) = o1.v[0]; *(float4*)(Y1 + off + 4) = o1.v[1];
    *(float4*)(Y2 + off) = o2.v[0]; *(float4*)(Y2 + off + 4) = o2.v[1];
  }
}

extern "C" void kernel_launch(void* const* d_in, const int* in_sizes, int n_in,
                              void* d_out, int out_size, void* d_ws, size_t ws_size,
                              hipStream_t stream) {
  const float* x1 = (const float*)d_in[0];
  const float* x2 = (const float*)d_in[1];
  const float* Wq = (const float*)d_in[2];
  const float* Wk = (const float*)d_in[3];
  const float* Wv = (const float*)d_in[4];
  const float* noise = (const float*)d_in[5];
  const float* W1 = (const float*)d_in[6];
  const float* b1 = (const float*)d_in[7];
  const float* W2 = (const float*)d_in[8];
  const float* b2 = (const float*)d_in[9];
  float* y = (float*)d_out;

  char* ws = (char*)d_ws;
  size_t off = 0;
  auto alloc = [&](size_t bytes) {
    char* p = ws + off;
    off += (bytes + 255) & ~(size_t)255;
    return p;
  };
  unsigned short* xb     = (unsigned short*)alloc((size_t)MTOT * D_ * 2);       // 100.7 MB
  unsigned short* vc     = (unsigned short*)alloc((size_t)MTOT * D_ * 2);       // 100.7 MB (v-half only)
  unsigned short* BtMain = (unsigned short*)alloc((size_t)2 * D_ * D_ * 2);     // [Wv^T | G]
  unsigned short* Wqb    = (unsigned short*)alloc((size_t)D_ * D_ * 2);
  unsigned short* Wkb    = (unsigned short*)alloc((size_t)D_ * D_ * 2);
  unsigned short* BtMlp  = (unsigned short*)alloc((size_t)NMLP * KMLP * 2);
  float* nk              = (float*)alloc((size_t)D_ * 4);
  float* gn              = (float*)alloc((size_t)D_ * 4);
  float* rel             = (float*)alloc((size_t)2 * ROWS * 4);
  float* dts             = (float*)alloc((size_t)4 * ROWS * 4);

  static bool attr_set = false;
  if (!attr_set) {
    (void)hipFuncSetAttribute((const void*)k_gemm256,
                              hipFuncAttributeMaxDynamicSharedMemorySize, 131072);
    attr_set = true;
  }

  hipMemsetAsync(rel, 0, (size_t)2 * ROWS * 4, stream);
  hipMemsetAsync(dts, 0, (size_t)4 * ROWS * 4, stream);

  k_convert_x<<<dim3(MTOT), 192, 0, stream>>>(x1, x2, xb);

  {
    int total = 3 * D_ * D_ + NMLP * KMLP;
    k_convert_w<<<dim3((total + 255) / 256), 256, 0, stream>>>(Wq, Wk, Wv, W1,
                                                               Wqb, Wkb, BtMain, BtMlp);
  }
  k_nk<<<dim3(3), 256, 0, stream>>>(noise, Wk, nk);
  k_gn<<<dim3(3), 256, 0, stream>>>(Wq, nk, gn);

  // G = Wq @ Wk^T (bf16) -> BtMain rows 768..1535
  k_gemm<6, false, D_><<<dim3(36), 256, 0, stream>>>(Wqb, Wkb, BtMain + (size_t)D_ * D_, D_);

  // main: v-half -> vc writes; c-half -> in-epilogue dots
  k_gemm256<<<dim3(1536), 512, 131072, stream>>>(xb, BtMain, vc, gn, dts);

  // MLP both dirs: rel logits
  k_gemm_mlp<<<dim3(768), 256, 0, stream>>>(xb, BtMlp, b1, W2, rel);

  // fusion
  k_fuse<<<dim3(ROWS / 4), 256, 0, stream>>>(x1, x2, vc, dts, rel, b2, y);
}

// Round 5
// 773.660 us; speedup vs baseline: 1.6650x; 1.0456x over previous
//
#include <hip/hip_runtime.h>
#include <cstdint>
#include <cstddef>

#define D_    768
#define ROWS  32768      // row pairs (B*N)
#define MTOT  65536      // interleaved rows: 2i = x1_i, 2i+1 = x2_i
#define HID   192
#define KMLP  1536
#define NMLP  384

#define NCX 8192         // prep blocks for convert_x (8 rows each)
#define NCW 12288        // prep blocks for convert_w (192 elems each)

typedef __attribute__((ext_vector_type(4))) float f32x4;
typedef __attribute__((ext_vector_type(8))) short s16x8;

__device__ inline unsigned short f2bf(float f) {
  union { float f; uint32_t u; } c; c.f = f;
  uint32_t r = c.u + 0x7FFFu + ((c.u >> 16) & 1u);
  return (unsigned short)(r >> 16);
}
__device__ inline float bf2f(unsigned short h) {
  union { uint32_t u; float f; } c; c.u = ((uint32_t)h) << 16;
  return c.f;
}

__device__ inline void gld_lds16(const void* g, void* l) {
  __builtin_amdgcn_global_load_lds(
      (const __attribute__((address_space(1))) void*)g,
      (__attribute__((address_space(3))) void*)l, 16, 0, 0);
}

// ---- prep mega-kernel (192 threads): convert_x | convert_w | nk
__global__ void k_prep(const float* __restrict__ x1, const float* __restrict__ x2,
                       unsigned short* __restrict__ xb,
                       const float* __restrict__ Wq, const float* __restrict__ Wk,
                       const float* __restrict__ Wv, const float* __restrict__ W1,
                       unsigned short* __restrict__ Wqb, unsigned short* __restrict__ Wkb,
                       unsigned short* __restrict__ BtMain, unsigned short* __restrict__ BtMlp,
                       const float* __restrict__ noise, float* __restrict__ nk) {
  const int bid = blockIdx.x;
  const int tid = threadIdx.x;
  if (bid < NCX) {
    // convert_x: 8 interleaved rows per block
    const int rbase = bid * 8;
    const int c = tid * 4;
#pragma unroll
    for (int rr = 0; rr < 8; ++rr) {
      const int r = rbase + rr;
      const float* src = ((r & 1) ? x2 : x1) + (size_t)(r >> 1) * D_ + c;
      float4 v = *(const float4*)src;
      union { unsigned short u[4]; uint2 p; } o;
      o.u[0] = f2bf(v.x); o.u[1] = f2bf(v.y); o.u[2] = f2bf(v.z); o.u[3] = f2bf(v.w);
      *(uint2*)(xb + (size_t)r * D_ + c) = o.p;
    }
    return;
  }
  if (bid < NCX + NCW) {
    int idx = (bid - NCX) * 192 + tid;
    const int S = D_ * D_;
    if (idx < S) { Wqb[idx] = f2bf(Wq[idx]); return; }
    idx -= S;
    if (idx < S) { Wkb[idx] = f2bf(Wk[idx]); return; }
    idx -= S;
    if (idx < S) {
      int n = idx / D_, k = idx - n * D_;
      BtMain[idx] = f2bf(Wv[(size_t)k * D_ + n]);
      return;
    }
    idx -= S;
    if (idx < NMLP * KMLP) {
      int n = idx / KMLP, k = idx - n * KMLP;
      int cc = (n < HID) ? n : n - HID;
      int kk = (n < HID) ? k : ((k < D_) ? k + D_ : k - D_);
      BtMlp[idx] = f2bf(W1[(size_t)kk * HID + cc]);
    }
    return;
  }
  // nk[j] = noise . Wk[:, j]
  const int j = (bid - NCX - NCW) * 192 + tid;
  if (j >= D_) return;
  float s = 0.f;
  for (int k = 0; k < D_; ++k) s += noise[k] * Wk[(size_t)k * D_ + j];
  nk[j] = s;
}

// ---- G = Wq@Wk^T (blocks 0..35, 128x128 bf16 tiles) | gn (blocks 36..38)
__launch_bounds__(256)
__global__ void k_ggemm_gn(const unsigned short* __restrict__ A,
                           const unsigned short* __restrict__ Bt,
                           unsigned short* __restrict__ C,
                           const float* __restrict__ Wq, const float* __restrict__ nk,
                           float* __restrict__ gn) {
  __shared__ __align__(16) short As[128 * 32];
  __shared__ __align__(16) short Bs[128 * 32];
  const int tid = threadIdx.x;
  const int id = blockIdx.x;
  if (id >= 36) {
    const int a = (id - 36) * 256 + tid;
    if (a < D_) {
      float s = 0.f;
      for (int j = 0; j < D_; ++j) s += Wq[(size_t)a * D_ + j] * nk[j];
      gn[a] = s;
    }
    return;
  }
  const int mi = id / 6, ni = id % 6;
  const int m0 = mi * 128, n0 = ni * 128;
  const int lane = tid & 63, wave = tid >> 6;
  const int wm = (wave >> 1) * 64, wn = (wave & 1) * 64;
  const int quad = lane >> 4, mr = lane & 15;
  f32x4 acc[4][4];
#pragma unroll
  for (int i = 0; i < 4; ++i)
#pragma unroll
    for (int j = 0; j < 4; ++j) acc[i][j] = (f32x4){0.f, 0.f, 0.f, 0.f};

  const int r = tid >> 2;
  const int q = (tid & 3) ^ ((r >> 1) & 3);
  const unsigned short* Ar0 = A + (size_t)(m0 + r) * D_ + q * 8;
  const unsigned short* Ar1 = A + (size_t)(m0 + 64 + r) * D_ + q * 8;
  const unsigned short* Br0 = Bt + (size_t)(n0 + r) * D_ + q * 8;
  const unsigned short* Br1 = Bt + (size_t)(n0 + 64 + r) * D_ + q * 8;

  int aoff[4], boff[4];
#pragma unroll
  for (int i = 0; i < 4; ++i) {
    int rl = wm + i * 16 + mr;
    aoff[i] = (rl * 4 + (quad ^ ((rl >> 1) & 3))) * 8;
    int nl = wn + i * 16 + mr;
    boff[i] = (nl * 4 + (quad ^ ((nl >> 1) & 3))) * 8;
  }

  for (int k0 = 0; k0 < D_; k0 += 32) {
    __syncthreads();
    gld_lds16(Ar0 + k0, &As[tid * 8]);
    gld_lds16(Ar1 + k0, &As[2048 + tid * 8]);
    gld_lds16(Br0 + k0, &Bs[tid * 8]);
    gld_lds16(Br1 + k0, &Bs[2048 + tid * 8]);
    __syncthreads();
    s16x8 a[4], b[4];
#pragma unroll
    for (int i = 0; i < 4; ++i) a[i] = *(const s16x8*)&As[aoff[i]];
#pragma unroll
    for (int j = 0; j < 4; ++j) b[j] = *(const s16x8*)&Bs[boff[j]];
#pragma unroll
    for (int i = 0; i < 4; ++i)
#pragma unroll
      for (int j = 0; j < 4; ++j)
        acc[i][j] = __builtin_amdgcn_mfma_f32_16x16x32_bf16(a[i], b[j], acc[i][j], 0, 0, 0);
  }
#pragma unroll
  for (int i = 0; i < 4; ++i) {
    int row = m0 + wm + i * 16 + quad * 4;
#pragma unroll
    for (int j = 0; j < 4; ++j) {
      int col = n0 + wn + j * 16 + mr;
#pragma unroll
      for (int t = 0; t < 4; ++t)
        C[(size_t)(row + t) * D_ + col] = f2bf(acc[i][j][t]);
    }
  }
}

// ---- main GEMM, 256x256 tile, BK=32, 4-slot ring, 3 slots in flight.
// 1024 threads = 16 waves (4M x 4N), per-wave 64x64 output -> acc[4][4] (64 AGPR).
// ~115 total regs/thread -> 16 waves/CU = 4 waves/SIMD (2x TLP vs r4's 512-thread).
// Schedule identical to r4 (validated): one barrier/slot, vmcnt(4) counted waits
// (2 loads/slot now: 1 gld A + 1 gld B per thread).
// c-half blocks (ni>=3): no C write; dots via global x re-read in epilogue.
__launch_bounds__(1024, 4)
__global__ void k_gemm256(const unsigned short* __restrict__ A,
                          const unsigned short* __restrict__ Bt,
                          unsigned short* __restrict__ C,
                          const float* __restrict__ gn,
                          float* __restrict__ dts) {
  extern __shared__ __align__(16) short lds[];
  const int tid = threadIdx.x;
  const int id = blockIdx.x;
  const int xcd = id & 7, tt = id >> 3;      // 1536 blocks, 192/XCD, same-m grouped
  const int mi = xcd * 32 + tt / 6;
  const int ni = tt % 6;
  const int m0 = mi * 256, n0 = ni * 256;
  const int lane = tid & 63, wave = tid >> 6;
  const int WM = (wave >> 2) * 64, WN = (wave & 3) * 64;
  const int quad = lane >> 4, mr = lane & 15;

  f32x4 acc[4][4];
#pragma unroll
  for (int i = 0; i < 4; ++i)
#pragma unroll
    for (int j = 0; j < 4; ++j) acc[i][j] = (f32x4){0.f, 0.f, 0.f, 0.f};

  // staging: thread tid -> row r0 = tid>>2 (0..255), lds chunk qt = tid&3;
  // global chunk pre-swizzled: q = qt ^ ((r0>>1)&3). LDS stays linear.
  const int r0 = tid >> 2;
  const int qg = ((tid & 3) ^ ((r0 >> 1) & 3)) * 8;
  const unsigned short* a0 = A + (size_t)(m0 + r0) * D_ + qg;
  const unsigned short* b0 = Bt + (size_t)(n0 + r0) * D_ + qg;
  const int ld0 = tid * 8;

  // ring slot layout (shorts): slot*16384 + { A[256][4][8] | B at +8192 }
#define STAGE_A(RNG, KT) gld_lds16(a0 + (KT) * 32, &lds[(RNG) * 16384 + ld0])
#define STAGE_B(RNG, KT) gld_lds16(b0 + (KT) * 32, &lds[(RNG) * 16384 + 8192 + ld0])

  const int chnk = (quad ^ ((mr >> 1) & 3)) * 8;
  const int abase = (WM + mr) * 32 + chnk;
  const int bbase = (WN + mr) * 32 + chnk;

  const bool cHalf = (ni >= 3);
  const int cc0 = n0 - D_;                       // c-half column origin

#define SLOT_BODY(S_, DOSTAGE_) do { \
  const int sb_ = ((S_) & 3) * 16384; \
  s16x8 aF[4], bF[4]; \
  _Pragma("unroll") \
  for (int j_ = 0; j_ < 4; ++j_) bF[j_] = *(const s16x8*)&lds[sb_ + 8192 + bbase + j_ * 512]; \
  _Pragma("unroll") \
  for (int i_ = 0; i_ < 4; ++i_) aF[i_] = *(const s16x8*)&lds[sb_ + abase + i_ * 512]; \
  if (DOSTAGE_) { STAGE_A(((S_) + 3) & 3, (S_) + 3); STAGE_B(((S_) + 3) & 3, (S_) + 3); } \
  __builtin_amdgcn_s_setprio(1); \
  _Pragma("unroll") \
  for (int i_ = 0; i_ < 4; ++i_) \
    _Pragma("unroll") \
    for (int j_ = 0; j_ < 4; ++j_) \
      acc[i_][j_] = __builtin_amdgcn_mfma_f32_16x16x32_bf16(aF[i_], bF[j_], acc[i_][j_], 0, 0, 0); \
  __builtin_amdgcn_s_setprio(0); \
} while (0)

  // prologue: stage data slots 0,1,2 into ring 0,1,2; wait slot 0 landed.
  STAGE_A(0, 0); STAGE_B(0, 0);
  STAGE_A(1, 1); STAGE_B(1, 1);
  STAGE_A(2, 2); STAGE_B(2, 2);
  asm volatile("s_waitcnt vmcnt(4)" ::: "memory");
  __builtin_amdgcn_s_barrier();

#pragma unroll 4
  for (int s = 0; s < 20; ++s) {
    SLOT_BODY(s, true);
    asm volatile("s_waitcnt vmcnt(4)" ::: "memory");
    __builtin_amdgcn_s_barrier();
  }
  // tail: slots 20..23 (slot 20 still stages data slot 23)
  SLOT_BODY(20, true);
  asm volatile("s_waitcnt vmcnt(4)" ::: "memory");
  __builtin_amdgcn_s_barrier();
  SLOT_BODY(21, false);
  asm volatile("s_waitcnt vmcnt(2)" ::: "memory");
  __builtin_amdgcn_s_barrier();
  SLOT_BODY(22, false);
  asm volatile("s_waitcnt vmcnt(0)" ::: "memory");
  __builtin_amdgcn_s_barrier();
  SLOT_BODY(23, false);

#undef SLOT_BODY
#undef STAGE_A
#undef STAGE_B

  if (!cHalf) {
    // v-half epilogue: write vc (ldc = 768)
#pragma unroll
    for (int i = 0; i < 4; ++i) {
      const int row = m0 + WM + i * 16 + quad * 4;
#pragma unroll
      for (int j = 0; j < 4; ++j) {
        const int col = n0 + WN + j * 16 + mr;
#pragma unroll
        for (int v = 0; v < 4; ++v)
          C[(size_t)(row + v) * D_ + col] = f2bf(acc[i][j][v]);
      }
    }
  } else {
    // c-half epilogue: partial dots via global x re-read (transient regs only)
#pragma unroll
    for (int i = 0; i < 4; ++i) {
      const int rb = m0 + WM + i * 16 + quad * 4;   // even row (pairs rb/2, rb/2+1)
      float xv[4][4], gv[4];
#pragma unroll
      for (int j = 0; j < 4; ++j) {
        const int cc = cc0 + WN + j * 16 + mr;
        gv[j] = gn[cc];
#pragma unroll
        for (int t = 0; t < 4; ++t)
          xv[t][j] = bf2f(A[(size_t)(rb + t) * D_ + cc]);
      }
      float d[2][4];
#pragma unroll
      for (int tp = 0; tp < 2; ++tp)
#pragma unroll
        for (int k = 0; k < 4; ++k) d[tp][k] = 0.f;
#pragma unroll
      for (int tp = 0; tp < 2; ++tp)
#pragma unroll
        for (int j = 0; j < 4; ++j) {
          const float c1 = acc[i][j][tp * 2], c2 = acc[i][j][tp * 2 + 1];
          const float a1v = xv[tp * 2][j], a2v = xv[tp * 2 + 1][j];
          d[tp][0] += a1v * (c1 + gv[j]);
          d[tp][1] += a1v * c2;
          d[tp][2] += a2v * c1;
          d[tp][3] += a2v * (c2 + gv[j]);
        }
#pragma unroll
      for (int m = 1; m < 16; m <<= 1)
#pragma unroll
        for (int tp = 0; tp < 2; ++tp)
#pragma unroll
          for (int k = 0; k < 4; ++k)
            d[tp][k] += __shfl_xor(d[tp][k], m, 64);
      if (mr == 0) {
#pragma unroll
        for (int tp = 0; tp < 2; ++tp) {
          const int p = (rb >> 1) + tp;
#pragma unroll
          for (int k = 0; k < 4; ++k)
            atomicAdd(&dts[(size_t)k * ROWS + p], d[tp][k]);
        }
      }
    }
  }
}

// ---- MLP GEMM: A = xb viewed [32768,1536], Bt = BtMlp [384,1536].
// T3-minimum 2-slot pipeline (32 KiB LDS, one barrier per K-step) at
// __launch_bounds__(256,4) -> ~4 blocks/CU of TLP.
__launch_bounds__(256, 4)
__global__ void k_gemm_mlp(const unsigned short* __restrict__ A,
                           const unsigned short* __restrict__ Bt,
                           const float* __restrict__ b1, const float* __restrict__ W2,
                           float* __restrict__ rel) {
  __shared__ __align__(16) short L[2 * 8192];   // slot: A[128][32] | B[128][32]
  const int tid = threadIdx.x;
  const int id = blockIdx.x;            // 768 blocks
  int t0 = id >> 3;
  const int mi = (id & 7) * 32 + t0 / 3;
  const int ni = t0 % 3;
  const int m0 = mi * 128, n0 = ni * 128;
  const int lane = tid & 63, wave = tid >> 6;
  const int wm = (wave >> 1) * 64, wn = (wave & 1) * 64;
  const int quad = lane >> 4, mr = lane & 15;
  f32x4 acc[4][4];
#pragma unroll
  for (int i = 0; i < 4; ++i)
#pragma unroll
    for (int j = 0; j < 4; ++j) acc[i][j] = (f32x4){0.f, 0.f, 0.f, 0.f};

  const int r = tid >> 2;
  const int q = (tid & 3) ^ ((r >> 1) & 3);
  const unsigned short* Ar0 = A + (size_t)(m0 + r) * KMLP + q * 8;
  const unsigned short* Ar1 = A + (size_t)(m0 + 64 + r) * KMLP + q * 8;
  const unsigned short* Br0 = Bt + (size_t)(n0 + r) * KMLP + q * 8;
  const unsigned short* Br1 = Bt + (size_t)(n0 + 64 + r) * KMLP + q * 8;

#define MSTAGE(SL, K0) do { \
    gld_lds16(Ar0 + (K0), &L[(SL) * 8192 + tid * 8]); \
    gld_lds16(Ar1 + (K0), &L[(SL) * 8192 + 2048 + tid * 8]); \
    gld_lds16(Br0 + (K0), &L[(SL) * 8192 + 4096 + tid * 8]); \
    gld_lds16(Br1 + (K0), &L[(SL) * 8192 + 4096 + 2048 + tid * 8]); } while (0)

  const int chnk = (quad ^ ((mr >> 1) & 3)) * 8;
  const int abase = (wm + mr) * 32 + chnk;
  const int bbase = (wn + mr) * 32 + chnk;

  MSTAGE(0, 0);
  asm volatile("s_waitcnt vmcnt(0)" ::: "memory");
  __builtin_amdgcn_s_barrier();

  for (int k0 = 0; k0 < KMLP; k0 += 64) {
#pragma unroll
    for (int h = 0; h < 2; ++h) {
      const int kk = k0 + h * 32;
      const int sb = h * 8192;
      if (kk + 32 < KMLP) MSTAGE(h ^ 1, kk + 32);
      s16x8 a[4], b[4];
#pragma unroll
      for (int j = 0; j < 4; ++j) b[j] = *(const s16x8*)&L[sb + 4096 + bbase + j * 512];
#pragma unroll
      for (int i = 0; i < 4; ++i) a[i] = *(const s16x8*)&L[sb + abase + i * 512];
      __builtin_amdgcn_s_setprio(1);
#pragma unroll
      for (int i = 0; i < 4; ++i)
#pragma unroll
        for (int j = 0; j < 4; ++j)
          acc[i][j] = __builtin_amdgcn_mfma_f32_16x16x32_bf16(a[i], b[j], acc[i][j], 0, 0, 0);
      __builtin_amdgcn_s_setprio(0);
      asm volatile("s_waitcnt vmcnt(0)" ::: "memory");
      __builtin_amdgcn_s_barrier();
    }
  }
#undef MSTAGE

  float part[2][4][4];
#pragma unroll
  for (int d = 0; d < 2; ++d)
#pragma unroll
    for (int i = 0; i < 4; ++i)
#pragma unroll
      for (int t = 0; t < 4; ++t) part[d][i][t] = 0.f;
#pragma unroll
  for (int j = 0; j < 4; ++j) {
    const int colb = n0 + wn + j * 16;        // wave-uniform
    const int dir = (colb >= HID) ? 1 : 0;
    const int cc = colb + mr - dir * HID;     // 0..191
    const float b1v = b1[cc];
    const float w2v = W2[cc];
#pragma unroll
    for (int i = 0; i < 4; ++i)
#pragma unroll
      for (int t = 0; t < 4; ++t) {
        float h = acc[i][j][t] + b1v;
        h = 0.5f * h * (1.f + erff(h * 0.70710678118654752f));
        part[dir][i][t] += h * w2v;
      }
  }
#pragma unroll
  for (int m = 1; m < 16; m <<= 1)
#pragma unroll
    for (int d = 0; d < 2; ++d)
#pragma unroll
      for (int i = 0; i < 4; ++i)
#pragma unroll
        for (int t = 0; t < 4; ++t)
          part[d][i][t] += __shfl_xor(part[d][i][t], m, 64);
  if (mr == 0) {
#pragma unroll
    for (int d = 0; d < 2; ++d)
#pragma unroll
      for (int i = 0; i < 4; ++i) {
        int p = m0 + wm + i * 16 + quad * 4;
#pragma unroll
        for (int t = 0; t < 4; ++t)
          atomicAdd(&rel[(size_t)d * ROWS + p + t], part[d][i][t]);
      }
  }
}

// ---- fusion: one wave per row-pair (dots precomputed by k_gemm256)
__launch_bounds__(256)
__global__ void k_fuse(const float* __restrict__ x1, const float* __restrict__ x2,
                       const unsigned short* __restrict__ vc,
                       const float* __restrict__ dts, const float* __restrict__ rel,
                       const float* __restrict__ b2, float* __restrict__ y) {
  const int p = blockIdx.x * 4 + (threadIdx.x >> 6);
  const int lane = threadIdx.x & 63;
  const unsigned short* L1 = vc + (size_t)(2 * p) * D_;
  const unsigned short* L2 = L1 + D_;
  const float* X1 = x1 + (size_t)p * D_;
  const float* X2 = x2 + (size_t)p * D_;
  const float scale = 0.0360843918243516f;   // 768^-0.5
  const float b2v = b2[0];
  const float d11 = dts[p], d12 = dts[ROWS + p];
  const float d21 = dts[2 * ROWS + p], d22 = dts[3 * ROWS + p];
  const float r1 = 1.f / (1.f + expf(-(rel[p] + b2v)));
  const float r2 = 1.f / (1.f + expf(-(rel[ROWS + p] + b2v)));
  const float ds1 = d11 * scale, dc1 = r1 * d12 * scale;
  const float ds2 = d22 * scale, dc2 = r2 * d21 * scale;
  const float ws1 = 1.f / (1.f + expf(dc1 - ds1)), wc1 = 1.f - ws1;
  const float ws2 = 1.f / (1.f + expf(dc2 - ds2)), wc2 = 1.f - ws2;
  float* Y1 = y + (size_t)p * D_;
  float* Y2 = y + (size_t)(ROWS + p) * D_;
  for (int c = lane; c < 96; c += 64) {
    const int off = c * 8;
    s16x8 v1 = *(const s16x8*)(L1 + off);
    s16x8 v2 = *(const s16x8*)(L2 + off);
    union F8 { float4 v[2]; float f[8]; };
    F8 a1, a2, o1, o2;
    a1.v[0] = *(const float4*)(X1 + off); a1.v[1] = *(const float4*)(X1 + off + 4);
    a2.v[0] = *(const float4*)(X2 + off); a2.v[1] = *(const float4*)(X2 + off + 4);
#pragma unroll
    for (int e = 0; e < 8; ++e) {
      float fv1 = bf2f(v1[e]), fv2 = bf2f(v2[e]);
      o1.f[e] = a1.f[e] + ws1 * fv1 + wc1 * fv2;
      o2.f[e] = a2.f[e] + ws2 * fv2 + wc2 * fv1;
    }
    *(float4*)(Y1 + off) = o1.v[0]; *(float4*)(Y1 + off + 4) = o1.v[1];
    *(float4*)(Y2 + off) = o2.v[0]; *(float4*)(Y2 + off + 4) = o2.v[1];
  }
}

extern "C" void kernel_launch(void* const* d_in, const int* in_sizes, int n_in,
                              void* d_out, int out_size, void* d_ws, size_t ws_size,
                              hipStream_t stream) {
  const float* x1 = (const float*)d_in[0];
  const float* x2 = (const float*)d_in[1];
  const float* Wq = (const float*)d_in[2];
  const float* Wk = (const float*)d_in[3];
  const float* Wv = (const float*)d_in[4];
  const float* noise = (const float*)d_in[5];
  const float* W1 = (const float*)d_in[6];
  const float* b1 = (const float*)d_in[7];
  const float* W2 = (const float*)d_in[8];
  const float* b2 = (const float*)d_in[9];
  float* y = (float*)d_out;

  char* ws = (char*)d_ws;
  size_t off = 0;
  auto alloc = [&](size_t bytes) {
    char* p = ws + off;
    off += (bytes + 255) & ~(size_t)255;
    return p;
  };
  unsigned short* xb     = (unsigned short*)alloc((size_t)MTOT * D_ * 2);       // 100.7 MB
  unsigned short* vc     = (unsigned short*)alloc((size_t)MTOT * D_ * 2);       // 100.7 MB (v-half only)
  unsigned short* BtMain = (unsigned short*)alloc((size_t)2 * D_ * D_ * 2);     // [Wv^T | G]
  unsigned short* Wqb    = (unsigned short*)alloc((size_t)D_ * D_ * 2);
  unsigned short* Wkb    = (unsigned short*)alloc((size_t)D_ * D_ * 2);
  unsigned short* BtMlp  = (unsigned short*)alloc((size_t)NMLP * KMLP * 2);
  float* nk              = (float*)alloc((size_t)D_ * 4);
  float* gn              = (float*)alloc((size_t)D_ * 4);
  float* scal            = (float*)alloc((size_t)6 * ROWS * 4);  // rel[2] | dts[4]
  float* rel             = scal;
  float* dts             = scal + 2 * ROWS;

  static bool attr_set = false;
  if (!attr_set) {
    (void)hipFuncSetAttribute((const void*)k_gemm256,
                              hipFuncAttributeMaxDynamicSharedMemorySize, 131072);
    attr_set = true;
  }

  hipMemsetAsync(scal, 0, (size_t)6 * ROWS * 4, stream);

  // prep: convert_x | convert_w | nk
  k_prep<<<dim3(NCX + NCW + 4), 192, 0, stream>>>(x1, x2, xb, Wq, Wk, Wv, W1,
                                                  Wqb, Wkb, BtMain, BtMlp, noise, nk);

  // G = Wq @ Wk^T -> BtMain rows 768..1535 | gn = Wq @ nk
  k_ggemm_gn<<<dim3(39), 256, 0, stream>>>(Wqb, Wkb, BtMain + (size_t)D_ * D_,
                                           Wq, nk, gn);

  // main: v-half -> vc writes; c-half -> in-epilogue dots
  k_gemm256<<<dim3(1536), 1024, 131072, stream>>>(xb, BtMain, vc, gn, dts);

  // MLP both dirs: rel logits
  k_gemm_mlp<<<dim3(768), 256, 0, stream>>>(xb, BtMlp, b1, W2, rel);

  // fusion
  k_fuse<<<dim3(ROWS / 4), 256, 0, stream>>>(x1, x2, vc, dts, rel, b2, y);
}